// Round 6
// baseline (740.244 us; speedup 1.0000x reference)
//
#include <hip/hip_runtime.h>
#include <stdint.h>

#define TS 2048
#define CD 128
#define NB 8
#define NROWS (NB*TS)          // 16384
#define RPB 8                  // rows per block in projection kernels
#define SCALE 0.08838834764831845f  // 1/sqrt(128)

// ---- scores kernel geometry ----
#define TQ 64                  // q-rows per block
#define TJ 256                 // j-tile width (= per-block j range)
#define JSPLIT 8
#define CH 64                  // Q staged in c-halves
#define CK 16                  // K c-chunk staged per sync
#define SKSTRIDE 260           // sK c4-group stride in float4 (256 + 4 pad)
#define SQH_FLOATS (TQ*CH)                 // 4096 floats (16 KB)
#define SK_FLOATS (4*SKSTRIDE*4)           // 4160 floats (16.6 KB)
#define SMEM_FLOATS (SQH_FLOATS + SK_FLOATS) // 8256 floats = 33 KB -> 4 blocks/CU

// ---- Kernel 1: Q = E@Wq^T, K = E@Wk^T (fp32), 8 rows per block ----
__global__ __launch_bounds__(128) void proj_qk(
    const float* __restrict__ E, const float* __restrict__ Wq,
    const float* __restrict__ Wk, float* __restrict__ Q, float* __restrict__ K)
{
    const int r0 = blockIdx.x * RPB, t = threadIdx.x;
    __shared__ float e[RPB][CD];
    {
        const float4* src = (const float4*)(E + (size_t)r0*CD);
        float4* dst = (float4*)&e[0][0];
        dst[t] = src[t];
        dst[t + 128] = src[t + 128];
    }
    __syncthreads();
    const float* wq = Wq + (size_t)t*CD;
    const float* wk = Wk + (size_t)t*CD;
    float aq[RPB], ak[RPB];
    #pragma unroll
    for (int i = 0; i < RPB; i++) { aq[i] = 0.f; ak[i] = 0.f; }
    #pragma unroll
    for (int c = 0; c < CD; c += 4) {
        float4 a = *(const float4*)(wq + c);
        float4 b = *(const float4*)(wk + c);
        #pragma unroll
        for (int i = 0; i < RPB; i++) {
            float e0 = e[i][c+0], e1 = e[i][c+1], e2 = e[i][c+2], e3 = e[i][c+3];
            aq[i] += a.x*e0 + a.y*e1 + a.z*e2 + a.w*e3;
            ak[i] += b.x*e0 + b.y*e1 + b.z*e2 + b.w*e3;
        }
    }
    #pragma unroll
    for (int i = 0; i < RPB; i++) {
        Q[(size_t)(r0+i)*CD + t] = aq[i];
        K[(size_t)(r0+i)*CD + t] = ak[i];
    }
}

// ---- Kernel 2: one 64x256 score tile per block + register top-3 + shfl merge ----
__global__ __launch_bounds__(256, 4) void scores_top3(
    const float* __restrict__ Q, const float* __restrict__ K, float* __restrict__ SPL)
{
    const int b  = blockIdx.x;           // 2048 = 8 n * 32 qtiles * 8 splits
    const int n  = b >> 8;
    const int qt = (b >> 3) & 31;
    const int sp = b & 7;
    const int q0 = qt * TQ;
    const int j0 = sp * TJ;
    const float* Kb = K + (size_t)n*TS*CD;
    const int tid = threadIdx.x;
    const int tj = tid & 31, tq = tid >> 5;   // tq in [0,8): rows tq*8..tq*8+7

    __shared__ float smem[SMEM_FLOATS];
    float*  sQh = smem;                         // [TQ][CH] row-major, c-half
    float4* sK  = (float4*)(smem + SQH_FLOATS); // [4 c4-groups][SKSTRIDE]

    float acc[8][8];
    #pragma unroll
    for (int i = 0; i < 8; i++)
        #pragma unroll
        for (int u = 0; u < 8; u++) acc[i][u] = 0.f;

    #pragma unroll 1
    for (int ch = 0; ch < 2; ch++) {
        __syncthreads();   // prior half's sQh reads complete
        {   // stage Q half: 64 rows x 64 c = 1024 float4, 4/thread
            #pragma unroll
            for (int i = 0; i < 4; i++) {
                int f4 = tid + 256*i;
                int row = f4 >> 4, c4 = f4 & 15;
                *(float4*)&sQh[row*CH + c4*4] =
                    *(const float4*)(Q + ((size_t)n*TS + q0 + row)*CD + ch*CH + c4*4);
            }
        }
        #pragma unroll 1
        for (int cc = 0; cc < 4; cc++) {       // 16-c chunks within half
            const int cbase = ch*CH + cc*CK;
            __syncthreads();   // sQh visible (first iter) / prior sK reads done
            #pragma unroll
            for (int s = 0; s < 4; s++) {      // stage K: 256 rows x 16 c, c4-grouped
                int j  = (tid >> 2) + 64*s;
                int c4 = tid & 3;
                float4 v = *(const float4*)(Kb + (size_t)(j0 + j)*CD + cbase + c4*4);
                sK[c4*SKSTRIDE + j] = v;
            }
            __syncthreads();
            #pragma unroll
            for (int c4 = 0; c4 < 4; c4++) {
                float4 kf[8];
                #pragma unroll
                for (int u = 0; u < 8; u++) kf[u] = sK[c4*SKSTRIDE + tj + 32*u];
                #pragma unroll
                for (int i = 0; i < 8; i++) {
                    float4 qf = *(const float4*)&sQh[(tq*8+i)*CH + cc*CK + c4*4];
                    #pragma unroll
                    for (int u = 0; u < 8; u++) {
                        acc[i][u] = __builtin_fmaf(qf.x, kf[u].x, acc[i][u]);
                        acc[i][u] = __builtin_fmaf(qf.y, kf[u].y, acc[i][u]);
                        acc[i][u] = __builtin_fmaf(qf.z, kf[u].z, acc[i][u]);
                        acc[i][u] = __builtin_fmaf(qf.w, kf[u].w, acc[i][u]);
                    }
                }
            }
        }
    }

    // per-thread top-3 per owned row (u ascending -> earliest index kept on ties)
    float t0v[8], t1v[8], t2v[8];
    int   t0i[8], t1i[8], t2i[8];
    #pragma unroll
    for (int i = 0; i < 8; i++) {
        t0v[i] = t1v[i] = t2v[i] = -3e38f;
        t0i[i] = t1i[i] = t2i[i] = 0x7fffffff;
    }
    #pragma unroll
    for (int i = 0; i < 8; i++) {
        #pragma unroll
        for (int u = 0; u < 8; u++) {
            float v = acc[i][u];
            if (v > t2v[i]) {
                int jg = j0 + tj + 32*u;
                if (v > t0v[i]) {
                    t2v[i]=t1v[i]; t2i[i]=t1i[i];
                    t1v[i]=t0v[i]; t1i[i]=t0i[i];
                    t0v[i]=v;      t0i[i]=jg;
                } else if (v > t1v[i]) {
                    t2v[i]=t1v[i]; t2i[i]=t1i[i];
                    t1v[i]=v;      t1i[i]=jg;
                } else {
                    t2v[i]=v;      t2i[i]=jg;
                }
            }
        }
    }

    // butterfly merge across the 32 lanes (tj) of each half-wave
    #pragma unroll
    for (int m = 16; m >= 1; m >>= 1) {
        #pragma unroll
        for (int i = 0; i < 8; i++) {
            float ov[3]; int oi[3];
            ov[0] = __shfl_xor(t0v[i], m); oi[0] = __shfl_xor(t0i[i], m);
            ov[1] = __shfl_xor(t1v[i], m); oi[1] = __shfl_xor(t1i[i], m);
            ov[2] = __shfl_xor(t2v[i], m); oi[2] = __shfl_xor(t2i[i], m);
            #pragma unroll
            for (int k = 0; k < 3; k++) {
                float v = ov[k]; int id = oi[k];
                bool g2 = (v > t2v[i]) || (v == t2v[i] && id < t2i[i]);
                if (g2) {
                    bool g0 = (v > t0v[i]) || (v == t0v[i] && id < t0i[i]);
                    bool g1 = (v > t1v[i]) || (v == t1v[i] && id < t1i[i]);
                    if (g0)      { t2v[i]=t1v[i];t2i[i]=t1i[i]; t1v[i]=t0v[i];t1i[i]=t0i[i]; t0v[i]=v;t0i[i]=id; }
                    else if (g1) { t2v[i]=t1v[i];t2i[i]=t1i[i]; t1v[i]=v;t1i[i]=id; }
                    else         { t2v[i]=v;t2i[i]=id; }
                }
            }
        }
    }
    if (tj == 0) {   // 8 writer threads (one per row-group)
        #pragma unroll
        for (int i = 0; i < 8; i++) {
            const int row = n*TS + q0 + tq*8 + i;
            float4* dst = (float4*)(SPL + ((size_t)row*JSPLIT + sp)*8);
            dst[0] = make_float4(t0v[i], __int_as_float(t0i[i]),
                                 t1v[i], __int_as_float(t1i[i]));
            dst[1] = make_float4(t2v[i], __int_as_float(t2i[i]), 0.f, 0.f);
        }
    }
}

// ---- Kernel 3: merge 8 splits per row -> global top-3 + 3-term softmax ----
__global__ __launch_bounds__(256) void merge_splits(
    const float* __restrict__ SPL, float* __restrict__ TOP)
{
    const int row = blockIdx.x*256 + threadIdx.x;   // 64 blocks -> 16384 rows
    const float* s = SPL + (size_t)row*JSPLIT*8;
    float b0v = -3e38f, b1v = -3e38f, b2v = -3e38f;
    int   b0i = 0x7fffffff, b1i = 0x7fffffff, b2i = 0x7fffffff;
    #pragma unroll
    for (int sp = 0; sp < JSPLIT; sp++) {
        #pragma unroll
        for (int k = 0; k < 3; k++) {
            float v = s[sp*8 + 2*k];
            int  id = __float_as_int(s[sp*8 + 2*k + 1]);
            bool g2 = (v > b2v) || (v == b2v && id < b2i);
            if (g2) {
                bool g0 = (v > b0v) || (v == b0v && id < b0i);
                bool g1 = (v > b1v) || (v == b1v && id < b1i);
                if (g0)      { b2v=b1v;b2i=b1i; b1v=b0v;b1i=b0i; b0v=v;b0i=id; }
                else if (g1) { b2v=b1v;b2i=b1i; b1v=v;  b1i=id; }
                else         { b2v=v;  b2i=id; }
            }
        }
    }
    float e1 = __expf((b1v - b0v)*SCALE);
    float e2 = __expf((b2v - b0v)*SCALE);
    float rz = 1.0f / (1.0f + e1 + e2);
    float* dst = TOP + (size_t)row*8;
    dst[0] = rz; dst[1] = e1*rz; dst[2] = e2*rz;
    int* di = (int*)dst;
    di[4] = b0i; di[5] = b1i; di[6] = b2i;
}

// ---- Kernel 4: materialize dense fp32 attention (zeros + 3 probs per row) ----
__global__ __launch_bounds__(256) void attn_write(
    const float* __restrict__ TOP, float* __restrict__ A)
{
    const int r = blockIdx.x, t = threadIdx.x;
    const float* s = TOP + (size_t)r*8;
    const int* si = (const int*)s;
    float p0 = s[0], p1 = s[1], p2 = s[2];
    int i0 = si[4], i1 = si[5], i2 = si[6];
    const int col0 = t*8;
    float vals[8];
    #pragma unroll
    for (int u = 0; u < 8; u++) {
        int col = col0 + u;
        float v = 0.f;
        if (col == i0) v = p0;
        if (col == i1) v = p1;
        if (col == i2) v = p2;
        vals[u] = v;
    }
    float4* dst = (float4*)(A + (size_t)r*TS + col0);
    dst[0] = make_float4(vals[0], vals[1], vals[2], vals[3]);
    dst[1] = make_float4(vals[4], vals[5], vals[6], vals[7]);
}

// ---- Kernel 5: out = (sum_k p_k * E[i_k]) @ Wo^T + bo, 8 rows per block ----
__global__ __launch_bounds__(128) void out_proj(
    const float* __restrict__ E, const float* __restrict__ Wo,
    const float* __restrict__ bo, const float* __restrict__ TOP,
    float* __restrict__ OUT)
{
    const int r0 = blockIdx.x * RPB, t = threadIdx.x;
    const int n = r0 >> 11;
    __shared__ float o[RPB][CD];
    #pragma unroll
    for (int i = 0; i < RPB; i++) {
        const float* s = TOP + (size_t)(r0+i)*8;
        const int* si = (const int*)s;
        const float* e0 = E + ((size_t)n*TS + si[4])*CD;
        const float* e1 = E + ((size_t)n*TS + si[5])*CD;
        const float* e2 = E + ((size_t)n*TS + si[6])*CD;
        o[i][t] = s[0]*e0[t] + s[1]*e1[t] + s[2]*e2[t];
    }
    __syncthreads();
    const float* wr = Wo + (size_t)t*CD;
    float acc[RPB];
    float bias = bo[t];
    #pragma unroll
    for (int i = 0; i < RPB; i++) acc[i] = bias;
    #pragma unroll
    for (int c = 0; c < CD; c += 4) {
        float4 a = *(const float4*)(wr + c);
        #pragma unroll
        for (int i = 0; i < RPB; i++)
            acc[i] += a.x*o[i][c+0] + a.y*o[i][c+1] + a.z*o[i][c+2] + a.w*o[i][c+3];
    }
    #pragma unroll
    for (int i = 0; i < RPB; i++)
        OUT[(size_t)(r0+i)*CD + t] = acc[i];
}

extern "C" void kernel_launch(void* const* d_in, const int* in_sizes, int n_in,
                              void* d_out, int out_size, void* d_ws, size_t ws_size,
                              hipStream_t stream)
{
    const float* E  = (const float*)d_in[0];
    // d_in[1] = ac, unused by the forward pass
    const float* Wq = (const float*)d_in[2];
    const float* Wk = (const float*)d_in[3];
    const float* Wo = (const float*)d_in[4];
    const float* bo = (const float*)d_in[5];

    float* Q   = (float*)d_ws;                       // 16384x128 fp32 (8 MB)
    float* K   = Q + (size_t)NROWS*CD;               // 8 MB
    float* TOP = K + (size_t)NROWS*CD;               // 16384x8 fp32 (512 KB)

    float* OUT = (float*)d_out;                      // [N,T,C] fp32
    float* A   = OUT + (size_t)NROWS*CD;             // [N,1,T,T] fp32
    float* SPL = A;   // scratch: 16384x8x8 fp32 = 4 MB, parked in A,
                      // consumed by merge_splits, then overwritten by attn_write

    proj_qk     <<<NROWS/RPB, 128, 0, stream>>>(E, Wq, Wk, Q, K);
    scores_top3 <<<NB*(TS/TQ)*JSPLIT, 256, 0, stream>>>(Q, K, SPL);
    merge_splits<<<NROWS/256, 256, 0, stream>>>(SPL, TOP);
    attn_write  <<<NROWS,     256, 0, stream>>>(TOP, A);
    out_proj    <<<NROWS/RPB, 128, 0, stream>>>(E, Wo, bo, TOP, OUT);
}

// Round 7
// 452.810 us; speedup vs baseline: 1.6348x; 1.6348x over previous
//
#include <hip/hip_runtime.h>
#include <stdint.h>

#define TS 2048
#define CD 128
#define NB 8
#define NROWS (NB*TS)          // 16384
#define RPB 8                  // rows per block in projection kernels
#define SCALE 0.08838834764831845f  // 1/sqrt(128)

// ---- scores kernel geometry ----
#define TQ 64                  // q-rows per block
#define TJ 256                 // j-tile width (= per-block j range)
#define JSPLIT 8
#define CH 64                  // Q staged in c-halves
#define CK 16                  // K c-chunk staged per sync
#define SKSTRIDE 260           // sK c4-group stride in float4 (256 + 4 pad)
#define SQH_FLOATS (TQ*CH)                 // 4096 floats (16 KB)
#define SK_FLOATS (4*SKSTRIDE*4)           // 4160 floats (16.6 KB)
#define SMEM_FLOATS (SQH_FLOATS + SK_FLOATS) // 8256 floats = 33 KB

// ---- Kernel 1: Q = E@Wq^T, K = E@Wk^T (fp32), 8 rows per block ----
__global__ __launch_bounds__(128) void proj_qk(
    const float* __restrict__ E, const float* __restrict__ Wq,
    const float* __restrict__ Wk, float* __restrict__ Q, float* __restrict__ K)
{
    const int r0 = blockIdx.x * RPB, t = threadIdx.x;
    __shared__ float e[RPB][CD];
    {
        const float4* src = (const float4*)(E + (size_t)r0*CD);
        float4* dst = (float4*)&e[0][0];
        dst[t] = src[t];
        dst[t + 128] = src[t + 128];
    }
    __syncthreads();
    const float* wq = Wq + (size_t)t*CD;
    const float* wk = Wk + (size_t)t*CD;
    float aq[RPB], ak[RPB];
    #pragma unroll
    for (int i = 0; i < RPB; i++) { aq[i] = 0.f; ak[i] = 0.f; }
    #pragma unroll
    for (int c = 0; c < CD; c += 4) {
        float4 a = *(const float4*)(wq + c);
        float4 b = *(const float4*)(wk + c);
        #pragma unroll
        for (int i = 0; i < RPB; i++) {
            float e0 = e[i][c+0], e1 = e[i][c+1], e2 = e[i][c+2], e3 = e[i][c+3];
            aq[i] += a.x*e0 + a.y*e1 + a.z*e2 + a.w*e3;
            ak[i] += b.x*e0 + b.y*e1 + b.z*e2 + b.w*e3;
        }
    }
    #pragma unroll
    for (int i = 0; i < RPB; i++) {
        Q[(size_t)(r0+i)*CD + t] = aq[i];
        K[(size_t)(r0+i)*CD + t] = ak[i];
    }
}

// ---- Kernel 2: one 64x256 score tile per block + register top-3 + shfl merge ----
// launch_bounds(256,3): 170-VGPR budget. (256,4) spilled acc[8][8] to scratch
// (r6: WRITE_SIZE 1.4 GB, 3x regression). Residency 3 blocks/CU (VGPR-capped).
__global__ __launch_bounds__(256, 3) void scores_top3(
    const float* __restrict__ Q, const float* __restrict__ K, float* __restrict__ SPL)
{
    const int b  = blockIdx.x;           // 2048 = 8 n * 32 qtiles * 8 splits
    const int n  = b >> 8;
    const int qt = (b >> 3) & 31;
    const int sp = b & 7;
    const int q0 = qt * TQ;
    const int j0 = sp * TJ;
    const float* Kb = K + (size_t)n*TS*CD;
    const int tid = threadIdx.x;
    const int tj = tid & 31, tq = tid >> 5;   // tq in [0,8): rows tq*8..tq*8+7

    __shared__ float smem[SMEM_FLOATS];
    float*  sQh = smem;                         // [TQ][CH] row-major, c-half
    float4* sK  = (float4*)(smem + SQH_FLOATS); // [4 c4-groups][SKSTRIDE]

    float acc[8][8];
    #pragma unroll
    for (int i = 0; i < 8; i++)
        #pragma unroll
        for (int u = 0; u < 8; u++) acc[i][u] = 0.f;

    #pragma unroll 1
    for (int ch = 0; ch < 2; ch++) {
        __syncthreads();   // prior half's sQh reads complete
        {   // stage Q half: 64 rows x 64 c = 1024 float4, 4/thread
            #pragma unroll
            for (int i = 0; i < 4; i++) {
                int f4 = tid + 256*i;
                int row = f4 >> 4, c4 = f4 & 15;
                *(float4*)&sQh[row*CH + c4*4] =
                    *(const float4*)(Q + ((size_t)n*TS + q0 + row)*CD + ch*CH + c4*4);
            }
        }
        #pragma unroll 1
        for (int cc = 0; cc < 4; cc++) {       // 16-c chunks within half
            const int cbase = ch*CH + cc*CK;
            __syncthreads();   // sQh visible (first iter) / prior sK reads done
            #pragma unroll
            for (int s = 0; s < 4; s++) {      // stage K: 256 rows x 16 c, c4-grouped
                int j  = (tid >> 2) + 64*s;
                int c4 = tid & 3;
                float4 v = *(const float4*)(Kb + (size_t)(j0 + j)*CD + cbase + c4*4);
                sK[c4*SKSTRIDE + j] = v;
            }
            __syncthreads();
            #pragma unroll
            for (int c4 = 0; c4 < 4; c4++) {
                float4 kf[8];
                #pragma unroll
                for (int u = 0; u < 8; u++) kf[u] = sK[c4*SKSTRIDE + tj + 32*u];
                #pragma unroll
                for (int i = 0; i < 8; i++) {
                    float4 qf = *(const float4*)&sQh[(tq*8+i)*CH + cc*CK + c4*4];
                    #pragma unroll
                    for (int u = 0; u < 8; u++) {
                        acc[i][u] = __builtin_fmaf(qf.x, kf[u].x, acc[i][u]);
                        acc[i][u] = __builtin_fmaf(qf.y, kf[u].y, acc[i][u]);
                        acc[i][u] = __builtin_fmaf(qf.z, kf[u].z, acc[i][u]);
                        acc[i][u] = __builtin_fmaf(qf.w, kf[u].w, acc[i][u]);
                    }
                }
            }
        }
    }

    // per-thread top-3 per owned row (u ascending -> earliest index kept on ties)
    float t0v[8], t1v[8], t2v[8];
    int   t0i[8], t1i[8], t2i[8];
    #pragma unroll
    for (int i = 0; i < 8; i++) {
        t0v[i] = t1v[i] = t2v[i] = -3e38f;
        t0i[i] = t1i[i] = t2i[i] = 0x7fffffff;
    }
    #pragma unroll
    for (int i = 0; i < 8; i++) {
        #pragma unroll
        for (int u = 0; u < 8; u++) {
            float v = acc[i][u];
            if (v > t2v[i]) {
                int jg = j0 + tj + 32*u;
                if (v > t0v[i]) {
                    t2v[i]=t1v[i]; t2i[i]=t1i[i];
                    t1v[i]=t0v[i]; t1i[i]=t0i[i];
                    t0v[i]=v;      t0i[i]=jg;
                } else if (v > t1v[i]) {
                    t2v[i]=t1v[i]; t2i[i]=t1i[i];
                    t1v[i]=v;      t1i[i]=jg;
                } else {
                    t2v[i]=v;      t2i[i]=jg;
                }
            }
        }
    }

    // butterfly merge across the 32 lanes (tj) of each half-wave
    #pragma unroll
    for (int m = 16; m >= 1; m >>= 1) {
        #pragma unroll
        for (int i = 0; i < 8; i++) {
            float ov[3]; int oi[3];
            ov[0] = __shfl_xor(t0v[i], m); oi[0] = __shfl_xor(t0i[i], m);
            ov[1] = __shfl_xor(t1v[i], m); oi[1] = __shfl_xor(t1i[i], m);
            ov[2] = __shfl_xor(t2v[i], m); oi[2] = __shfl_xor(t2i[i], m);
            #pragma unroll
            for (int k = 0; k < 3; k++) {
                float v = ov[k]; int id = oi[k];
                bool g2 = (v > t2v[i]) || (v == t2v[i] && id < t2i[i]);
                if (g2) {
                    bool g0 = (v > t0v[i]) || (v == t0v[i] && id < t0i[i]);
                    bool g1 = (v > t1v[i]) || (v == t1v[i] && id < t1i[i]);
                    if (g0)      { t2v[i]=t1v[i];t2i[i]=t1i[i]; t1v[i]=t0v[i];t1i[i]=t0i[i]; t0v[i]=v;t0i[i]=id; }
                    else if (g1) { t2v[i]=t1v[i];t2i[i]=t1i[i]; t1v[i]=v;t1i[i]=id; }
                    else         { t2v[i]=v;t2i[i]=id; }
                }
            }
        }
    }
    if (tj == 0) {   // 8 writer threads (one per row-group)
        #pragma unroll
        for (int i = 0; i < 8; i++) {
            const int row = n*TS + q0 + tq*8 + i;
            float4* dst = (float4*)(SPL + ((size_t)row*JSPLIT + sp)*8);
            dst[0] = make_float4(t0v[i], __int_as_float(t0i[i]),
                                 t1v[i], __int_as_float(t1i[i]));
            dst[1] = make_float4(t2v[i], __int_as_float(t2i[i]), 0.f, 0.f);
        }
    }
}

// ---- Kernel 3: merge 8 splits per row -> global top-3 + 3-term softmax ----
__global__ __launch_bounds__(256) void merge_splits(
    const float* __restrict__ SPL, float* __restrict__ TOP)
{
    const int row = blockIdx.x*256 + threadIdx.x;   // 64 blocks -> 16384 rows
    const float* s = SPL + (size_t)row*JSPLIT*8;
    float b0v = -3e38f, b1v = -3e38f, b2v = -3e38f;
    int   b0i = 0x7fffffff, b1i = 0x7fffffff, b2i = 0x7fffffff;
    #pragma unroll
    for (int sp = 0; sp < JSPLIT; sp++) {
        #pragma unroll
        for (int k = 0; k < 3; k++) {
            float v = s[sp*8 + 2*k];
            int  id = __float_as_int(s[sp*8 + 2*k + 1]);
            bool g2 = (v > b2v) || (v == b2v && id < b2i);
            if (g2) {
                bool g0 = (v > b0v) || (v == b0v && id < b0i);
                bool g1 = (v > b1v) || (v == b1v && id < b1i);
                if (g0)      { b2v=b1v;b2i=b1i; b1v=b0v;b1i=b0i; b0v=v;b0i=id; }
                else if (g1) { b2v=b1v;b2i=b1i; b1v=v;  b1i=id; }
                else         { b2v=v;  b2i=id; }
            }
        }
    }
    float e1 = __expf((b1v - b0v)*SCALE);
    float e2 = __expf((b2v - b0v)*SCALE);
    float rz = 1.0f / (1.0f + e1 + e2);
    float* dst = TOP + (size_t)row*8;
    dst[0] = rz; dst[1] = e1*rz; dst[2] = e2*rz;
    int* di = (int*)dst;
    di[4] = b0i; di[5] = b1i; di[6] = b2i;
}

// ---- Kernel 4: materialize dense fp32 attention (zeros + 3 probs per row) ----
__global__ __launch_bounds__(256) void attn_write(
    const float* __restrict__ TOP, float* __restrict__ A)
{
    const int r = blockIdx.x, t = threadIdx.x;
    const float* s = TOP + (size_t)r*8;
    const int* si = (const int*)s;
    float p0 = s[0], p1 = s[1], p2 = s[2];
    int i0 = si[4], i1 = si[5], i2 = si[6];
    const int col0 = t*8;
    float vals[8];
    #pragma unroll
    for (int u = 0; u < 8; u++) {
        int col = col0 + u;
        float v = 0.f;
        if (col == i0) v = p0;
        if (col == i1) v = p1;
        if (col == i2) v = p2;
        vals[u] = v;
    }
    float4* dst = (float4*)(A + (size_t)r*TS + col0);
    dst[0] = make_float4(vals[0], vals[1], vals[2], vals[3]);
    dst[1] = make_float4(vals[4], vals[5], vals[6], vals[7]);
}

// ---- Kernel 5: out = (sum_k p_k * E[i_k]) @ Wo^T + bo, 8 rows per block ----
__global__ __launch_bounds__(128) void out_proj(
    const float* __restrict__ E, const float* __restrict__ Wo,
    const float* __restrict__ bo, const float* __restrict__ TOP,
    float* __restrict__ OUT)
{
    const int r0 = blockIdx.x * RPB, t = threadIdx.x;
    const int n = r0 >> 11;
    __shared__ float o[RPB][CD];
    #pragma unroll
    for (int i = 0; i < RPB; i++) {
        const float* s = TOP + (size_t)(r0+i)*8;
        const int* si = (const int*)s;
        const float* e0 = E + ((size_t)n*TS + si[4])*CD;
        const float* e1 = E + ((size_t)n*TS + si[5])*CD;
        const float* e2 = E + ((size_t)n*TS + si[6])*CD;
        o[i][t] = s[0]*e0[t] + s[1]*e1[t] + s[2]*e2[t];
    }
    __syncthreads();
    const float* wr = Wo + (size_t)t*CD;
    float acc[RPB];
    float bias = bo[t];
    #pragma unroll
    for (int i = 0; i < RPB; i++) acc[i] = bias;
    #pragma unroll
    for (int c = 0; c < CD; c += 4) {
        float4 a = *(const float4*)(wr + c);
        #pragma unroll
        for (int i = 0; i < RPB; i++)
            acc[i] += a.x*o[i][c+0] + a.y*o[i][c+1] + a.z*o[i][c+2] + a.w*o[i][c+3];
    }
    #pragma unroll
    for (int i = 0; i < RPB; i++)
        OUT[(size_t)(r0+i)*CD + t] = acc[i];
}

extern "C" void kernel_launch(void* const* d_in, const int* in_sizes, int n_in,
                              void* d_out, int out_size, void* d_ws, size_t ws_size,
                              hipStream_t stream)
{
    const float* E  = (const float*)d_in[0];
    // d_in[1] = ac, unused by the forward pass
    const float* Wq = (const float*)d_in[2];
    const float* Wk = (const float*)d_in[3];
    const float* Wo = (const float*)d_in[4];
    const float* bo = (const float*)d_in[5];

    float* Q   = (float*)d_ws;                       // 16384x128 fp32 (8 MB)
    float* K   = Q + (size_t)NROWS*CD;               // 8 MB
    float* TOP = K + (size_t)NROWS*CD;               // 16384x8 fp32 (512 KB)

    float* OUT = (float*)d_out;                      // [N,T,C] fp32
    float* A   = OUT + (size_t)NROWS*CD;             // [N,1,T,T] fp32
    float* SPL = A;   // scratch: 16384x8x8 fp32 = 4 MB, parked in A,
                      // consumed by merge_splits, then overwritten by attn_write

    proj_qk     <<<NROWS/RPB, 128, 0, stream>>>(E, Wq, Wk, Q, K);
    scores_top3 <<<NB*(TS/TQ)*JSPLIT, 256, 0, stream>>>(Q, K, SPL);
    merge_splits<<<NROWS/256, 256, 0, stream>>>(SPL, TOP);
    attn_write  <<<NROWS,     256, 0, stream>>>(TOP, A);
    out_proj    <<<NROWS/RPB, 128, 0, stream>>>(E, Wo, bo, TOP, OUT);
}